// Round 12
// baseline (1668.177 us; speedup 1.0000x reference)
//
#include <hip/hip_runtime.h>

#define NB 8
#define NPTS 16384
#define S 1024
#define KNEI 32
#define MROWS (NB*S*KNEI)   // 262144

typedef float v2f __attribute__((ext_vector_type(2)));

// Value-only f32 max combine via DPP, bound_ctrl=1 (invalid lanes read 0 --
// safe identity: all reduced values are >= 0).
#define DPP_MAXF0(CTRL, v) do {                                               \
    int _o = __builtin_amdgcn_update_dpp(0, __float_as_int(v),                \
                                         (CTRL), 0xF, 0xF, true);             \
    (v) = fmaxf((v), __int_as_float(_o));                                     \
  } while (0)

// i32 min combine via DPP, identity INT_MAX via the 'old' operand
// (bound_ctrl=false keeps old where the source lane is invalid).
#define DPP_MINI(CTRL, v) do {                                                \
    int _o = __builtin_amdgcn_update_dpp((int)0x7fffffff, (v),                \
                                         (CTRL), 0xF, 0xF, false);            \
    (v) = (_o < (v)) ? _o : (v);                                              \
  } while (0)

// u64 key max combine via DPP halves, bound_ctrl=1 (identity 0 always loses:
// every real key >= 1 because of the 16384-idx field). Cross-wave stage only.
#define DPP_MAXK0(CTRL, k) do {                                               \
    int _olo = __builtin_amdgcn_update_dpp(0, (int)(unsigned)(k),             \
                                           (CTRL), 0xF, 0xF, true);           \
    int _ohi = __builtin_amdgcn_update_dpp(0, (int)(unsigned)((k) >> 32),     \
                                           (CTRL), 0xF, 0xF, true);           \
    unsigned long long _ok = (((unsigned long long)(unsigned)_ohi) << 32)     \
                           | (unsigned)_olo;                                  \
    if (_ok > (k)) (k) = _ok;                                                 \
  } while (0)

#define DPP_ROW_SHR1   0x111
#define DPP_ROW_SHR2   0x112
#define DPP_ROW_SHR4   0x114
#define DPP_ROW_SHR8   0x118
#define DPP_ROW_BCAST15 0x142
#define DPP_ROW_BCAST31 0x143

// ---------------------------------------------------------------------------
// FPS r20 = r18's measured 1145us structure UNCHANGED (plain v2f dist loop;
// r19's inline-asm v_pk_* is dropped -- VOP3P pair-alignment risk in inline
// asm is the prime suspect for the container kill). Morton box-skip,
// key-only wave caching, speculative coord prefetch all as measured.
// Exact-match discipline: contract off, ((dx^2+dy^2)+dz^2) order, key =
// dist_bits<<15 | (16384-orig_idx) == numpy first-occurrence argmax.
// ---------------------------------------------------------------------------
__global__ __launch_bounds__(1024, 4) void fps_kernel(const float* __restrict__ pos,
                                                      float* __restrict__ centers,
                                                      float* __restrict__ sbuf){
#pragma clang fp contract(off)
  __shared__ int hist[4096];
  __shared__ int ts[1024];
  __shared__ unsigned short perm[16384];
  __shared__ unsigned long long lslotK[2][16];
  const int b = blockIdx.x;
  const int t = threadIdx.x;
  const int wid = t >> 6, lane = t & 63;
  const float* pb = pos + (size_t)b * NPTS * 3;
  float* ssx = sbuf + (size_t)b * 3 * NPTS;
  float* ssy = ssx + NPTS;
  float* ssz = ssy + NPTS;
  const int p0 = t * 16;

  // ---- phase 0: load raw points, Morton cell ids ----
  float c[48];
  {
    const float4* src = (const float4*)(pb + (size_t)t*48);
#pragma unroll
    for (int q = 0; q < 12; ++q) *(float4*)&c[q*4] = src[q];
  }
  int cell[16];
#pragma unroll
  for (int j = 0; j < 16; ++j){
    float x = c[3*j], y = c[3*j+1], z = c[3*j+2];
    int ix = (int)(x * 16.f); ix = ix < 0 ? 0 : (ix > 15 ? 15 : ix);
    int iy = (int)(y * 16.f); iy = iy < 0 ? 0 : (iy > 15 ? 15 : iy);
    int iz = (int)(z * 16.f); iz = iz < 0 ? 0 : (iz > 15 ? 15 : iz);
    int m = 0;
#pragma unroll
    for (int k = 0; k < 4; ++k){
      m |= ((ix >> k) & 1) << (3*k + 2);
      m |= ((iy >> k) & 1) << (3*k + 1);
      m |= ((iz >> k) & 1) << (3*k + 0);
    }
    cell[j] = m;
  }
#pragma unroll
  for (int i = 0; i < 4; ++i) hist[t*4 + i] = 0;
  __syncthreads();
#pragma unroll
  for (int j = 0; j < 16; ++j) atomicAdd(&hist[cell[j]], 1);
  __syncthreads();
  int h0 = hist[t*4], h1 = hist[t*4+1], h2v = hist[t*4+2];
  ts[t] = h0 + h1 + h2v + hist[t*4+3];
  __syncthreads();
  for (int off = 1; off < 1024; off <<= 1){
    int add = (t >= off) ? ts[t - off] : 0;
    __syncthreads();
    ts[t] += add;
    __syncthreads();
  }
  {
    int base = (t == 0) ? 0 : ts[t-1];
    hist[t*4]   = base;
    hist[t*4+1] = base + h0;
    hist[t*4+2] = base + h0 + h1;
    hist[t*4+3] = base + h0 + h1 + h2v;
  }
  __syncthreads();
#pragma unroll
  for (int j = 0; j < 16; ++j){
    int dst = atomicAdd(&hist[cell[j]], 1);
    ssx[dst] = c[3*j];
    ssy[dst] = c[3*j+1];
    ssz[dst] = c[3*j+2];
    perm[dst] = (unsigned short)(p0 + j);
  }
  __syncthreads();

  // ---- reload sorted points into registers; box; orig-idx pairs ----
  v2f px[8], py[8], pz[8], dist[8];
  int perm_reg[8];
#pragma unroll
  for (int g = 0; g < 4; ++g){
    float4 vx = *(const float4*)&ssx[p0 + g*4];
    float4 vy = *(const float4*)&ssy[p0 + g*4];
    float4 vz = *(const float4*)&ssz[p0 + g*4];
    px[g*2]   = (v2f){vx.x, vx.y}; px[g*2+1] = (v2f){vx.z, vx.w};
    py[g*2]   = (v2f){vy.x, vy.y}; py[g*2+1] = (v2f){vy.z, vy.w};
    pz[g*2]   = (v2f){vz.x, vz.y}; pz[g*2+1] = (v2f){vz.z, vz.w};
  }
#pragma unroll
  for (int j = 0; j < 8; ++j){
    perm_reg[j] = (int)perm[p0 + 2*j] | ((int)perm[p0 + 2*j + 1] << 16);
  }
  float bxl = 1e30f, bxh = -1e30f, byl = 1e30f, byh = -1e30f;
  float bzl = 1e30f, bzh = -1e30f;
#pragma unroll
  for (int j = 0; j < 8; ++j){
    asm volatile("" : "+v"(px[j]), "+v"(py[j]), "+v"(pz[j]), "+v"(perm_reg[j]));
    bxl = fminf(bxl, fminf(px[j].x, px[j].y));
    bxh = fmaxf(bxh, fmaxf(px[j].x, px[j].y));
    byl = fminf(byl, fminf(py[j].x, py[j].y));
    byh = fmaxf(byh, fmaxf(py[j].x, py[j].y));
    bzl = fminf(bzl, fminf(pz[j].x, pz[j].y));
    bzh = fmaxf(bzh, fmaxf(pz[j].x, pz[j].y));
    dist[j] = (v2f){1e10f, 1e10f};
  }
  float ub = 1e10f;
  unsigned long long key = 0;                  // cached wave-reduced key
  float cx = pb[0], cy = pb[1], cz = pb[2];    // far=0 initial centroid

  // ---- phase 1: the serial FPS loop ----
  for (int s = 0; s < S; ++s){
    if (t == 0){
      float* cd = centers + (size_t)(b*S + s)*3;
      cd[0] = cx; cd[1] = cy; cd[2] = cz;
    }
    float lx = fmaxf(fmaxf(bxl - cx, cx - bxh), 0.f);
    float ly = fmaxf(fmaxf(byl - cy, cy - byh), 0.f);
    float lz = fmaxf(fmaxf(bzl - cz, cz - bzh), 0.f);
    float lb2 = ((lx*lx + ly*ly) + lz*lz);
    bool act = !(lb2 * 0.99999f >= ub);
    unsigned long long am = __ballot((int)act);
    if (am){                               // wave-uniform branch
      if (act){
        v2f cx2 = (v2f){cx, cx}, cy2 = (v2f){cy, cy}, cz2 = (v2f){cz, cz};
        float nb = 0.0f;
#pragma unroll
        for (int j = 0; j < 8; ++j){
          v2f dx = px[j] - cx2;
          v2f dy = py[j] - cy2;
          v2f dz = pz[j] - cz2;
          v2f t1 = dx * dx;
          v2f t2 = dy * dy;
          v2f t3 = dz * dz;
          v2f d  = (t1 + t2) + t3;         // ((dx^2+dy^2)+dz^2)
          v2f od = dist[j];
          v2f nd = (v2f){__builtin_fminf(od.x, d.x), __builtin_fminf(od.y, d.y)};
          dist[j] = nd;
          nb = fmaxf(fmaxf(nb, nd.x), nd.y);   // v_max3
        }
        ub = nb;
      }
      float bv = ub;
      DPP_MAXF0(DPP_ROW_SHR1,   bv);
      DPP_MAXF0(DPP_ROW_SHR2,   bv);
      DPP_MAXF0(DPP_ROW_SHR4,   bv);
      DPP_MAXF0(DPP_ROW_SHR8,   bv);
      DPP_MAXF0(DPP_ROW_BCAST15, bv);
      DPP_MAXF0(DPP_ROW_BCAST31, bv);
      float bmw = __int_as_float(
          __builtin_amdgcn_readlane(__float_as_int(bv), 63));
      int mi = 0x7fffffff;
      if (ub == bmw){
#pragma unroll
        for (int j = 0; j < 8; ++j){
          if (dist[j].x == bmw){ int o = perm_reg[j] & 0xffff;         mi = o < mi ? o : mi; }
          if (dist[j].y == bmw){ int o = (perm_reg[j] >> 16) & 0xffff; mi = o < mi ? o : mi; }
        }
      }
      DPP_MINI(DPP_ROW_SHR1,   mi);
      DPP_MINI(DPP_ROW_SHR2,   mi);
      DPP_MINI(DPP_ROW_SHR4,   mi);
      DPP_MINI(DPP_ROW_SHR8,   mi);
      DPP_MINI(DPP_ROW_BCAST15, mi);
      DPP_MINI(DPP_ROW_BCAST31, mi);
      int miw = __builtin_amdgcn_readlane(mi, 63);
      key = ((unsigned long long)__float_as_uint(bmw) << 15)
          | (unsigned long long)(16384 - miw);
    }
    const int par = s & 1;
    if (lane == 0) lslotK[par][wid] = key;
    __syncthreads();
    // per-lane slot read + speculative coord prefetch (overlaps the chain)
    unsigned long long kk = lslotK[par][lane & 15];
    int ufi_l = 16384 - (int)(kk & 0x7FFFull);
    const float* cpl = pb + (size_t)ufi_l*3;
    float wx = cpl[0], wy = cpl[1], wz = cpl[2];
    unsigned long long kko = kk;
    DPP_MAXK0(DPP_ROW_SHR1, kk);
    DPP_MAXK0(DPP_ROW_SHR2, kk);
    DPP_MAXK0(DPP_ROW_SHR4, kk);
    DPP_MAXK0(DPP_ROW_SHR8, kk);
    unsigned blo = (unsigned)__builtin_amdgcn_readlane((int)(unsigned)kk, 15);
    unsigned bhi = (unsigned)__builtin_amdgcn_readlane((int)(unsigned)(kk >> 32), 15);
    unsigned long long bkmax = (((unsigned long long)bhi) << 32) | blo;
    unsigned m16 = (unsigned)__ballot((int)(kko == bkmax)) & 0xffffu;
    int sidx = (int)__builtin_ctz(m16);        // uniform (SGPR)
    cx = __int_as_float(__builtin_amdgcn_readlane(__float_as_int(wx), sidx));
    cy = __int_as_float(__builtin_amdgcn_readlane(__float_as_int(wy), sidx));
    cz = __int_as_float(__builtin_amdgcn_readlane(__float_as_int(wz), sidx));
  }
}

// ---------------------------------------------------------------------------
// Ball query (+ stats zeroing). One wave per center; ordered compaction of
// the first 32 in-radius indices (== jnp.sort-then-truncate).
// ---------------------------------------------------------------------------
__global__ __launch_bounds__(256) void ballq_kernel(const float* __restrict__ pos,
                                                    const float* __restrict__ centers,
                                                    int* __restrict__ idx,
                                                    float* __restrict__ stats){
#pragma clang fp contract(off)
  if (blockIdx.x < 3) stats[blockIdx.x*256 + threadIdx.x] = 0.f;
  const float R2 = (float)(0.2*0.2);   // match Python double 0.2*0.2 -> f32
  int wid  = blockIdx.x*4 + (threadIdx.x >> 6);
  int lane = threadIdx.x & 63;
  int b = wid >> 10;                   // wid / S
  const float* pb = pos + (size_t)b * NPTS * 3;
  float cx = centers[wid*3+0], cy = centers[wid*3+1], cz = centers[wid*3+2];
  int* out = idx + wid*KNEI;
  int count = 0; int first = -1;
  for (int base = 0; base < NPTS; base += 64){
    int p = base + lane;
    float dx = pb[p*3+0]-cx, dy = pb[p*3+1]-cy, dz = pb[p*3+2]-cz;
    float t1 = dx*dx, t2 = dy*dy, t3 = dz*dz;
    float d = (t1 + t2) + t3;
    bool inr = d <= R2;
    unsigned long long mask = __ballot(inr);
    if (count == 0 && mask) first = base + __builtin_ctzll(mask);
    if (inr){
      int slot = count + __popcll(mask & ((1ull << lane) - 1ull));
      if (slot < KNEI) out[slot] = p;
    }
    count += __popcll(mask);
    if (count >= KNEI) break;
  }
  if (count < KNEI){
    for (int slot = count + lane; slot < KNEI; slot += 64) out[slot] = first;
  }
}

// ---------------------------------------------------------------------------
// GEMM1 both branches in ONE kernel (8192 blocks). sem x-tile stored
// TRANSPOSED (xst[k][r], 66-wide pad) so inner-loop reads are broadcast
// across 8 banks (was 8-way conflicted at [64][68] row reads).
// ---------------------------------------------------------------------------
__global__ __launch_bounds__(256) void gemm1_both(const float* __restrict__ feat,
    const float* __restrict__ pos, const float* __restrict__ centers,
    const int* __restrict__ idx,
    const float* __restrict__ w_s, const float* __restrict__ b_s,
    float* __restrict__ h1s, float* __restrict__ st_s,
    const float* __restrict__ w_g, const float* __restrict__ b_g,
    float* __restrict__ h1g, float* __restrict__ st_g){
  __shared__ float smem[8448];           // union of both branch layouts
  const int tid = threadIdx.x;
  if (blockIdx.x < (MROWS/64)){
    // ------------------- sem branch -------------------
    float (*xst)[66] = (float(*)[66])smem;          // 64 (k) x 66 (r)
    float (*wsh)[64] = (float(*)[64])(smem + 4224); // 64x64
    const int m0 = blockIdx.x * 64;
#pragma unroll
    for (int i = 0; i < 4; ++i){
      int q = tid + i*256;
      int r = q >> 4, c4 = q & 15;
      *(float4*)&wsh[r][c4*4] = *(const float4*)&w_s[r*64 + c4*4];
    }
#pragma unroll
    for (int i = 0; i < 4; ++i){
      int q = tid + i*256;
      int r = q >> 4, c4 = q & 15;
      int m = m0 + r;
      int nb = idx[m];
      int b = m >> 15;
      const float* fr = feat + ((size_t)b*NPTS + nb)*64;
      float4 v = *(const float4*)&fr[c4*4];
      xst[c4*4+0][r] = v.x;
      xst[c4*4+1][r] = v.y;
      xst[c4*4+2][r] = v.z;
      xst[c4*4+3][r] = v.w;
    }
    __syncthreads();
    const int g  = tid & 7;
    const int rt = tid >> 3;
    const int r0 = rt * 2;
    float acc[2][8];
#pragma unroll
    for (int c = 0; c < 8; ++c){ float bb = b_s[g*8+c]; acc[0][c] = bb; acc[1][c] = bb; }
    for (int k = 0; k < 64; ++k){
      float x0 = xst[k][r0], x1 = xst[k][r0+1];
      float4 wa = *(float4*)&wsh[k][g*8];
      float4 wb = *(float4*)&wsh[k][g*8+4];
      float wv[8] = {wa.x,wa.y,wa.z,wa.w,wb.x,wb.y,wb.z,wb.w};
#pragma unroll
      for (int c = 0; c < 8; ++c){ acc[0][c] += x0*wv[c]; acc[1][c] += x1*wv[c]; }
    }
#pragma unroll
    for (int r = 0; r < 2; ++r){
      float* dst = h1s + (size_t)(m0 + r0 + r)*64 + g*8;
      *(float4*)dst     = make_float4(acc[r][0],acc[r][1],acc[r][2],acc[r][3]);
      *(float4*)(dst+4) = make_float4(acc[r][4],acc[r][5],acc[r][6],acc[r][7]);
    }
    float ls[8], lq[8];
#pragma unroll
    for (int c = 0; c < 8; ++c){
      ls[c] = acc[0][c] + acc[1][c];
      lq[c] = acc[0][c]*acc[0][c] + acc[1][c]*acc[1][c];
    }
    __syncthreads();
    float* red  = smem;
    float* redq = smem + 4224;
#pragma unroll
    for (int c = 0; c < 8; ++c){
      red[(g*8+c)*32 + rt]  = ls[c];
      redq[(g*8+c)*32 + rt] = lq[c];
    }
    __syncthreads();
    if (tid < 128){
      int c = tid & 63;
      const float* src = (tid < 64) ? red : redq;
      float a2 = 0.f;
      for (int i = 0; i < 32; ++i) a2 += src[c*32+i];
      atomicAdd(&st_s[(tid < 64 ? 0 : 64) + c], a2);
    }
  } else {
    // ------------------- geo branch -------------------
    float (*xs)[8]   = (float(*)[8])smem;            // 64x8
    float (*wsh)[64] = (float(*)[64])(smem + 512);   // 6x64
    float* red  = smem + 896;                        // 2048
    float* redq = smem + 2944;                       // 2048
    const int m0 = (blockIdx.x - (MROWS/64)) * 64;
    for (int i = tid; i < 384; i += 256) wsh[i >> 6][i & 63] = w_g[i];
    if (tid < 64){
      int m = m0 + tid;
      int grp = m >> 5;
      int b = m >> 15;
      int nb = idx[m];
      const float* cp = centers + (size_t)grp*3;
      const float* pp = pos + ((size_t)b*NPTS + nb)*3;
      xs[tid][0]=cp[0]; xs[tid][1]=cp[1]; xs[tid][2]=cp[2];
      xs[tid][3]=pp[0]; xs[tid][4]=pp[1]; xs[tid][5]=pp[2];
    }
    __syncthreads();
    const int g  = tid & 7;
    const int rt = tid >> 3;
    const int r0 = rt * 2;
    float acc[2][8];
#pragma unroll
    for (int c = 0; c < 8; ++c){ float bb = b_g[g*8+c]; acc[0][c]=bb; acc[1][c]=bb; }
#pragma unroll
    for (int k = 0; k < 6; ++k){
      float x0 = xs[r0][k], x1 = xs[r0+1][k];
      float4 wa = *(float4*)&wsh[k][g*8];
      float4 wb = *(float4*)&wsh[k][g*8+4];
      float wv[8] = {wa.x,wa.y,wa.z,wa.w,wb.x,wb.y,wb.z,wb.w};
#pragma unroll
      for (int c = 0; c < 8; ++c){ acc[0][c] += x0*wv[c]; acc[1][c] += x1*wv[c]; }
    }
#pragma unroll
    for (int r = 0; r < 2; ++r){
      float* dst = h1g + (size_t)(m0 + r0 + r)*64 + g*8;
      *(float4*)dst     = make_float4(acc[r][0],acc[r][1],acc[r][2],acc[r][3]);
      *(float4*)(dst+4) = make_float4(acc[r][4],acc[r][5],acc[r][6],acc[r][7]);
    }
    float ls[8], lq[8];
#pragma unroll
    for (int c = 0; c < 8; ++c){
      ls[c] = acc[0][c] + acc[1][c];
      lq[c] = acc[0][c]*acc[0][c] + acc[1][c]*acc[1][c];
    }
#pragma unroll
    for (int c = 0; c < 8; ++c){
      red[(g*8+c)*32 + rt]  = ls[c];
      redq[(g*8+c)*32 + rt] = lq[c];
    }
    __syncthreads();
    if (tid < 128){
      int c = tid & 63;
      const float* src = (tid < 64) ? red : redq;
      float a2 = 0.f;
      for (int i = 0; i < 32; ++i) a2 += src[c*32+i];
      atomicAdd(&st_g[(tid < 64 ? 0 : 64) + c], a2);
    }
  }
}

// ---------------------------------------------------------------------------
// GEMM2 both branches (8192 blocks), fused max-over-k, BN1 fold computed
// IN-BLOCK from layer-1 stats (removes the bn_finalize launch). x-tile
// transposed (xst[k][r], 66-wide) for bank-free reads. Monotone-affine max
// commutation (a>0) as r16.
// ---------------------------------------------------------------------------
__global__ __launch_bounds__(256) void gemm2_both(
    const float* __restrict__ h1s, const float* __restrict__ st1,
    const float* __restrict__ g1,  const float* __restrict__ be1,
    const float* __restrict__ w_s2, const float* __restrict__ b_s2,
    float* __restrict__ hmax1, float* __restrict__ st2,
    const float* __restrict__ h1g, const float* __restrict__ st3,
    const float* __restrict__ g3,  const float* __restrict__ be3,
    const float* __restrict__ w_g2, const float* __restrict__ b_g2,
    float* __restrict__ hmax2, float* __restrict__ st4){
  __shared__ float smem[12416];          // xst 4224 | wsh 8192
  __shared__ float abuf[64], dbuf[64];
  const int tid = threadIdx.x;
  const bool sem = blockIdx.x < (MROWS/64);
  const int bx = sem ? blockIdx.x : blockIdx.x - (MROWS/64);
  const float* hin  = sem ? h1s  : h1g;
  const float* w    = sem ? w_s2 : w_g2;
  const float* bias = sem ? b_s2 : b_g2;
  float* hmax       = sem ? hmax1 : hmax2;
  float* stat       = sem ? st2  : st4;
  float (*xst)[66]  = (float(*)[66])smem;
  float (*wsh)[128] = (float(*)[128])(smem + 4224);
  const int m0 = bx * 64;
  // BN1 fold from stats (identical math to old bn_finalize)
  if (tid < 64){
    const float* st  = sem ? st1 : st3;
    const float* gam = sem ? g1  : g3;
    const float* bet = sem ? be1 : be3;
    const float invM = 1.0f / (float)MROWS;
    float mu  = st[tid] * invM;
    float ex2 = st[64 + tid] * invM;
    float var = ex2 - mu*mu;
    float aa = gam[tid] * rsqrtf(var + 1e-5f);
    abuf[tid] = aa;
    dbuf[tid] = bet[tid] - mu*aa;
  }
  __syncthreads();
#pragma unroll
  for (int i = 0; i < 8; ++i){
    int q = tid + i*256;                 // 2048 quads of w (64x128)
    int r = q >> 5, c4 = q & 31;
    *(float4*)&wsh[r][c4*4] = *(const float4*)&w[r*128 + c4*4];
  }
#pragma unroll
  for (int i = 0; i < 4; ++i){
    int q = tid + i*256;
    int r = q >> 4, c4 = q & 15;
    float4 v = *(const float4*)&hin[(size_t)(m0+r)*64 + c4*4];
    float a0 = abuf[c4*4+0], aA = abuf[c4*4+1], aB = abuf[c4*4+2], aC = abuf[c4*4+3];
    float d0 = dbuf[c4*4+0], dA = dbuf[c4*4+1], dB = dbuf[c4*4+2], dC = dbuf[c4*4+3];
    v.x = fmaxf(v.x*a0 + d0, 0.f);
    v.y = fmaxf(v.y*aA + dA, 0.f);
    v.z = fmaxf(v.z*aB + dB, 0.f);
    v.w = fmaxf(v.w*aC + dC, 0.f);
    xst[c4*4+0][r] = v.x;
    xst[c4*4+1][r] = v.y;
    xst[c4*4+2][r] = v.z;
    xst[c4*4+3][r] = v.w;
  }
  __syncthreads();
  const int g  = tid & 15;               // 16 groups x 8 ch = 128
  const int rt = tid >> 4;               // 16 row-threads x 4 rows = 64
  const int r0 = rt * 4;
  float acc[4][8];
#pragma unroll
  for (int c = 0; c < 8; ++c){
    float bb = bias[g*8+c];
    acc[0][c]=bb; acc[1][c]=bb; acc[2][c]=bb; acc[3][c]=bb;
  }
  for (int k = 0; k < 64; ++k){
    float x0 = xst[k][r0], x1 = xst[k][r0+1], x2 = xst[k][r0+2], x3 = xst[k][r0+3];
    float4 wa = *(float4*)&wsh[k][g*8];
    float4 wb = *(float4*)&wsh[k][g*8+4];
    float wv[8] = {wa.x,wa.y,wa.z,wa.w,wb.x,wb.y,wb.z,wb.w};
#pragma unroll
    for (int c = 0; c < 8; ++c){
      acc[0][c] += x0*wv[c]; acc[1][c] += x1*wv[c];
      acc[2][c] += x2*wv[c]; acc[3][c] += x3*wv[c];
    }
  }
  float ls[8], lq[8], tmax[8];
#pragma unroll
  for (int c = 0; c < 8; ++c){
    ls[c] = acc[0][c]+acc[1][c]+acc[2][c]+acc[3][c];
    lq[c] = acc[0][c]*acc[0][c]+acc[1][c]*acc[1][c]+acc[2][c]*acc[2][c]+acc[3][c]*acc[3][c];
    tmax[c] = fmaxf(fmaxf(acc[0][c],acc[1][c]), fmaxf(acc[2][c],acc[3][c]));
  }
  __syncthreads();
  float* red  = smem;                    // 2048 sums + 2048 sumsq (xst area)
  float* mred = smem + 4224;             // 16 x 128 maxes (wsh area)
#pragma unroll
  for (int c = 0; c < 8; ++c){
    red[(g*8+c)*16 + rt]        = ls[c];
    red[2048 + (g*8+c)*16 + rt] = lq[c];
    mred[rt*128 + g*8 + c]      = tmax[c];
  }
  __syncthreads();
  {
    int c = tid & 127;
    int isq = tid >> 7;
    float a2 = 0.f;
    for (int i = 0; i < 16; ++i) a2 += red[isq*2048 + c*16 + i];
    atomicAdd(&stat[isq*128 + c], a2);
  }
  {
    int og = tid >> 7;                   // 0..1 (k-group within block)
    int c  = tid & 127;
    float m = -3.4e38f;
#pragma unroll
    for (int i = 0; i < 8; ++i) m = fmaxf(m, mred[(og*8 + i)*128 + c]);
    hmax[(size_t)(bx*2 + og)*128 + c] = m;
  }
}

// ---------------------------------------------------------------------------
// BN apply on pooled maxes, BN2 fold computed per-thread from stats
// (removes the second bn_finalize launch). Exact: a>0 monotone affine.
// ---------------------------------------------------------------------------
__global__ __launch_bounds__(256) void bnapply_both(const float* __restrict__ hmax1,
    const float* __restrict__ st2, const float* __restrict__ g2,
    const float* __restrict__ be2,
    const float* __restrict__ hmax2,
    const float* __restrict__ st4, const float* __restrict__ g4,
    const float* __restrict__ be4,
    float* __restrict__ out){
  const int half = NB*S*128;
  int i = blockIdx.x*256 + threadIdx.x;
  bool semh = i < half;
  int j = semh ? i : i - half;
  int c = j & 127;
  const float* st  = semh ? st2 : st4;
  const float* gam = semh ? g2  : g4;
  const float* bet = semh ? be2 : be4;
  const float invM = 1.0f / (float)MROWS;
  float mu  = st[c] * invM;
  float ex2 = st[128 + c] * invM;
  float var = ex2 - mu*mu;
  float aa = gam[c] * rsqrtf(var + 1e-5f);
  float dd = bet[c] - mu*aa;
  float hv = semh ? hmax1[j] : hmax2[j];
  out[i] = fmaxf(hv*aa + dd, 0.f);
}

extern "C" void kernel_launch(void* const* d_in, const int* in_sizes, int n_in,
                              void* d_out, int out_size, void* d_ws, size_t ws_size,
                              hipStream_t stream){
  const float* pos   = (const float*)d_in[0];
  const float* feat  = (const float*)d_in[1];
  const float* w_s1  = (const float*)d_in[2];
  const float* b_s1  = (const float*)d_in[3];
  const float* g_s1  = (const float*)d_in[4];
  const float* be_s1 = (const float*)d_in[5];
  const float* w_s2  = (const float*)d_in[6];
  const float* b_s2  = (const float*)d_in[7];
  const float* g_s2  = (const float*)d_in[8];
  const float* be_s2 = (const float*)d_in[9];
  const float* w_g1  = (const float*)d_in[10];
  const float* b_g1  = (const float*)d_in[11];
  const float* g_g1  = (const float*)d_in[12];
  const float* be_g1 = (const float*)d_in[13];
  const float* w_g2  = (const float*)d_in[14];
  const float* b_g2  = (const float*)d_in[15];
  const float* g_g2  = (const float*)d_in[16];
  const float* be_g2 = (const float*)d_in[17];
  float* outp = (float*)d_out;
  float* wsf  = (float*)d_ws;

  // workspace layout (floats):
  float* centers = wsf;                          // 24576
  int*   idxp    = (int*)(wsf + 24576);          // 262144
  float* stats   = wsf + 24576 + 262144;         // 768
  float* h1s     = wsf + 288256;                 // MROWS*64 = 16777216
  float* h1g     = h1s + (size_t)MROWS*64;       // 16777216
  float* sortbuf = h1g + (size_t)MROWS*64;       // 393216
  float* hmax1   = sortbuf + 393216;             // 1048576
  float* hmax2   = hmax1 + 1048576;              // 1048576

  float* st1 = stats;        // 64 sum + 64 sq
  float* st2 = stats + 128;  // 128 + 128
  float* st3 = stats + 384;  // 64 + 64
  float* st4 = stats + 512;  // 128 + 128

  fps_kernel<<<NB, 1024, 0, stream>>>(pos, centers, sortbuf);
  ballq_kernel<<<(NB*S)/4, 256, 0, stream>>>(pos, centers, idxp, stats);
  gemm1_both<<<2*(MROWS/64), 256, 0, stream>>>(feat, pos, centers, idxp,
      w_s1, b_s1, h1s, st1, w_g1, b_g1, h1g, st3);
  gemm2_both<<<2*(MROWS/64), 256, 0, stream>>>(
      h1s, st1, g_s1, be_s1, w_s2, b_s2, hmax1, st2,
      h1g, st3, g_g1, be_g1, w_g2, b_g2, hmax2, st4);
  bnapply_both<<<(2*NB*S*128)/256, 256, 0, stream>>>(
      hmax1, st2, g_s2, be_s2, hmax2, st4, g_g2, be_g2, outp);
}

// Round 13
// 1618.025 us; speedup vs baseline: 1.0310x; 1.0310x over previous
//
#include <hip/hip_runtime.h>

#define NB 8
#define NPTS 16384
#define S 1024
#define KNEI 32
#define MROWS (NB*S*KNEI)   // 262144

typedef float v2f __attribute__((ext_vector_type(2)));

// Value-only f32 max combine via DPP, bound_ctrl=1 (invalid lanes read 0 --
// safe identity: all reduced values are >= 0).
#define DPP_MAXF0(CTRL, v) do {                                               \
    int _o = __builtin_amdgcn_update_dpp(0, __float_as_int(v),                \
                                         (CTRL), 0xF, 0xF, true);             \
    (v) = fmaxf((v), __int_as_float(_o));                                     \
  } while (0)

// i32 min combine via DPP, identity INT_MAX via the 'old' operand
// (bound_ctrl=false keeps old where the source lane is invalid).
#define DPP_MINI(CTRL, v) do {                                                \
    int _o = __builtin_amdgcn_update_dpp((int)0x7fffffff, (v),                \
                                         (CTRL), 0xF, 0xF, false);            \
    (v) = (_o < (v)) ? _o : (v);                                              \
  } while (0)

#define DPP_ROW_SHR1   0x111
#define DPP_ROW_SHR2   0x112
#define DPP_ROW_SHR4   0x114
#define DPP_ROW_SHR8   0x118
#define DPP_ROW_BCAST15 0x142
#define DPP_ROW_BCAST31 0x143

// ---------------------------------------------------------------------------
// FPS r21 = r20 (1148us) with the cross-wave reduce replaced by ONE LDS u64
// atomicMax on a TAG-MONOTONE key:
//   key = (s+1)<<47 | dist_bits<<15 | (16384-idx)
// Tag dominance => no reset / parity / spin: step-s keys beat all older keys.
// Lane 63 of each wave atomic-maxes pre-barrier (staggered -> ~1 atomic
// latency on the critical path); post-barrier all threads read the single
// cell (broadcast) and load winner coords (uniform, L2-hot). Skipped waves
// republish their cached key with the tag bumped (dists unchanged => value
// fields still exact); the previous winner's wave is always active, so the
// cell always carries a current-tag key. Removes ~50 instr/wave/step
// (slot read + 4-stage u64 DPP chain + ballot/readlane select).
// Exactness unchanged: contract off, ((dx^2+dy^2)+dz^2), lexicographic
// (max dist, min orig idx) == numpy first-occurrence argmax.
// ---------------------------------------------------------------------------
__global__ __launch_bounds__(1024, 4) void fps_kernel(const float* __restrict__ pos,
                                                      float* __restrict__ centers,
                                                      float* __restrict__ sbuf){
#pragma clang fp contract(off)
  __shared__ int hist[4096];
  __shared__ int ts[1024];
  __shared__ unsigned short perm[16384];
  __shared__ unsigned long long wincell;
  const int b = blockIdx.x;
  const int t = threadIdx.x;
  const int lane = t & 63;
  const float* pb = pos + (size_t)b * NPTS * 3;
  float* ssx = sbuf + (size_t)b * 3 * NPTS;
  float* ssy = ssx + NPTS;
  float* ssz = ssy + NPTS;
  const int p0 = t * 16;

  // ---- phase 0: load raw points, Morton cell ids ----
  float c[48];
  {
    const float4* src = (const float4*)(pb + (size_t)t*48);
#pragma unroll
    for (int q = 0; q < 12; ++q) *(float4*)&c[q*4] = src[q];
  }
  int cell[16];
#pragma unroll
  for (int j = 0; j < 16; ++j){
    float x = c[3*j], y = c[3*j+1], z = c[3*j+2];
    int ix = (int)(x * 16.f); ix = ix < 0 ? 0 : (ix > 15 ? 15 : ix);
    int iy = (int)(y * 16.f); iy = iy < 0 ? 0 : (iy > 15 ? 15 : iy);
    int iz = (int)(z * 16.f); iz = iz < 0 ? 0 : (iz > 15 ? 15 : iz);
    int m = 0;
#pragma unroll
    for (int k = 0; k < 4; ++k){
      m |= ((ix >> k) & 1) << (3*k + 2);
      m |= ((iy >> k) & 1) << (3*k + 1);
      m |= ((iz >> k) & 1) << (3*k + 0);
    }
    cell[j] = m;
  }
#pragma unroll
  for (int i = 0; i < 4; ++i) hist[t*4 + i] = 0;
  __syncthreads();
#pragma unroll
  for (int j = 0; j < 16; ++j) atomicAdd(&hist[cell[j]], 1);
  __syncthreads();
  int h0 = hist[t*4], h1 = hist[t*4+1], h2v = hist[t*4+2];
  ts[t] = h0 + h1 + h2v + hist[t*4+3];
  __syncthreads();
  for (int off = 1; off < 1024; off <<= 1){
    int add = (t >= off) ? ts[t - off] : 0;
    __syncthreads();
    ts[t] += add;
    __syncthreads();
  }
  {
    int base = (t == 0) ? 0 : ts[t-1];
    hist[t*4]   = base;
    hist[t*4+1] = base + h0;
    hist[t*4+2] = base + h0 + h1;
    hist[t*4+3] = base + h0 + h1 + h2v;
  }
  __syncthreads();
#pragma unroll
  for (int j = 0; j < 16; ++j){
    int dst = atomicAdd(&hist[cell[j]], 1);
    ssx[dst] = c[3*j];
    ssy[dst] = c[3*j+1];
    ssz[dst] = c[3*j+2];
    perm[dst] = (unsigned short)(p0 + j);
  }
  if (t == 0) wincell = 0ull;
  __syncthreads();

  // ---- reload sorted points into registers; box; orig-idx pairs ----
  v2f px[8], py[8], pz[8], dist[8];
  int perm_reg[8];
#pragma unroll
  for (int g = 0; g < 4; ++g){
    float4 vx = *(const float4*)&ssx[p0 + g*4];
    float4 vy = *(const float4*)&ssy[p0 + g*4];
    float4 vz = *(const float4*)&ssz[p0 + g*4];
    px[g*2]   = (v2f){vx.x, vx.y}; px[g*2+1] = (v2f){vx.z, vx.w};
    py[g*2]   = (v2f){vy.x, vy.y}; py[g*2+1] = (v2f){vy.z, vy.w};
    pz[g*2]   = (v2f){vz.x, vz.y}; pz[g*2+1] = (v2f){vz.z, vz.w};
  }
#pragma unroll
  for (int j = 0; j < 8; ++j){
    perm_reg[j] = (int)perm[p0 + 2*j] | ((int)perm[p0 + 2*j + 1] << 16);
  }
  float bxl = 1e30f, bxh = -1e30f, byl = 1e30f, byh = -1e30f;
  float bzl = 1e30f, bzh = -1e30f;
#pragma unroll
  for (int j = 0; j < 8; ++j){
    asm volatile("" : "+v"(px[j]), "+v"(py[j]), "+v"(pz[j]), "+v"(perm_reg[j]));
    bxl = fminf(bxl, fminf(px[j].x, px[j].y));
    bxh = fmaxf(bxh, fmaxf(px[j].x, px[j].y));
    byl = fminf(byl, fminf(py[j].x, py[j].y));
    byh = fmaxf(byh, fmaxf(py[j].x, py[j].y));
    bzl = fminf(bzl, fminf(pz[j].x, pz[j].y));
    bzh = fmaxf(bzh, fmaxf(pz[j].x, pz[j].y));
    dist[j] = (v2f){1e10f, 1e10f};
  }
  float ub = 1e10f;
  unsigned long long key = 0;                  // cached wave key (value bits)
  float cx = pb[0], cy = pb[1], cz = pb[2];    // far=0 initial centroid

  // ---- phase 1: the serial FPS loop ----
  for (int s = 0; s < S; ++s){
    if (t == 0){
      float* cd = centers + (size_t)(b*S + s)*3;
      cd[0] = cx; cd[1] = cy; cd[2] = cz;
    }
    const unsigned long long tag = (unsigned long long)(s + 1) << 47;
    float lx = fmaxf(fmaxf(bxl - cx, cx - bxh), 0.f);
    float ly = fmaxf(fmaxf(byl - cy, cy - byh), 0.f);
    float lz = fmaxf(fmaxf(bzl - cz, cz - bzh), 0.f);
    float lb2 = ((lx*lx + ly*ly) + lz*lz);
    bool act = !(lb2 * 0.99999f >= ub);
    unsigned long long am = __ballot((int)act);
    if (am){                               // wave-uniform branch
      if (act){
        v2f cx2 = (v2f){cx, cx}, cy2 = (v2f){cy, cy}, cz2 = (v2f){cz, cz};
        float nb = 0.0f;
#pragma unroll
        for (int j = 0; j < 8; ++j){
          v2f dx = px[j] - cx2;
          v2f dy = py[j] - cy2;
          v2f dz = pz[j] - cz2;
          v2f t1 = dx * dx;
          v2f t2 = dy * dy;
          v2f t3 = dz * dz;
          v2f d  = (t1 + t2) + t3;         // ((dx^2+dy^2)+dz^2)
          v2f od = dist[j];
          v2f nd = (v2f){__builtin_fminf(od.x, d.x), __builtin_fminf(od.y, d.y)};
          dist[j] = nd;
          nb = fmaxf(fmaxf(nb, nd.x), nd.y);   // v_max3
        }
        ub = nb;
      }
      float bv = ub;
      DPP_MAXF0(DPP_ROW_SHR1,   bv);
      DPP_MAXF0(DPP_ROW_SHR2,   bv);
      DPP_MAXF0(DPP_ROW_SHR4,   bv);
      DPP_MAXF0(DPP_ROW_SHR8,   bv);
      DPP_MAXF0(DPP_ROW_BCAST15, bv);
      DPP_MAXF0(DPP_ROW_BCAST31, bv);
      float bmw = __int_as_float(
          __builtin_amdgcn_readlane(__float_as_int(bv), 63));
      int mi = 0x7fffffff;
      if (ub == bmw){
#pragma unroll
        for (int j = 0; j < 8; ++j){
          if (dist[j].x == bmw){ int o = perm_reg[j] & 0xffff;         mi = o < mi ? o : mi; }
          if (dist[j].y == bmw){ int o = (perm_reg[j] >> 16) & 0xffff; mi = o < mi ? o : mi; }
        }
      }
      DPP_MINI(DPP_ROW_SHR1,   mi);
      DPP_MINI(DPP_ROW_SHR2,   mi);
      DPP_MINI(DPP_ROW_SHR4,   mi);
      DPP_MINI(DPP_ROW_SHR8,   mi);
      DPP_MINI(DPP_ROW_BCAST15, mi);
      DPP_MINI(DPP_ROW_BCAST31, mi);
      int miw = __builtin_amdgcn_readlane(mi, 63);
      key = ((unsigned long long)__float_as_uint(bmw) << 15)
          | (unsigned long long)(16384 - miw);        // value bits only
    }
    // publish: tag-monotone atomic (skipped waves republish cached value)
    if (lane == 63) atomicMax(&wincell, tag | key);
    __syncthreads();
    unsigned long long wk = wincell;            // broadcast read
    int ufi = 16384 - (int)(wk & 0x7FFFull);
    const float* cp = pb + (size_t)ufi*3;       // uniform, L2-hot
    cx = cp[0]; cy = cp[1]; cz = cp[2];
  }
}

// ---------------------------------------------------------------------------
// Ball query (+ stats zeroing). One wave per center; ordered compaction of
// the first 32 in-radius indices (== jnp.sort-then-truncate).
// ---------------------------------------------------------------------------
__global__ __launch_bounds__(256) void ballq_kernel(const float* __restrict__ pos,
                                                    const float* __restrict__ centers,
                                                    int* __restrict__ idx,
                                                    float* __restrict__ stats){
#pragma clang fp contract(off)
  if (blockIdx.x < 3) stats[blockIdx.x*256 + threadIdx.x] = 0.f;
  const float R2 = (float)(0.2*0.2);   // match Python double 0.2*0.2 -> f32
  int wid  = blockIdx.x*4 + (threadIdx.x >> 6);
  int lane = threadIdx.x & 63;
  int b = wid >> 10;                   // wid / S
  const float* pb = pos + (size_t)b * NPTS * 3;
  float cx = centers[wid*3+0], cy = centers[wid*3+1], cz = centers[wid*3+2];
  int* out = idx + wid*KNEI;
  int count = 0; int first = -1;
  for (int base = 0; base < NPTS; base += 64){
    int p = base + lane;
    float dx = pb[p*3+0]-cx, dy = pb[p*3+1]-cy, dz = pb[p*3+2]-cz;
    float t1 = dx*dx, t2 = dy*dy, t3 = dz*dz;
    float d = (t1 + t2) + t3;
    bool inr = d <= R2;
    unsigned long long mask = __ballot(inr);
    if (count == 0 && mask) first = base + __builtin_ctzll(mask);
    if (inr){
      int slot = count + __popcll(mask & ((1ull << lane) - 1ull));
      if (slot < KNEI) out[slot] = p;
    }
    count += __popcll(mask);
    if (count >= KNEI) break;
  }
  if (count < KNEI){
    for (int slot = count + lane; slot < KNEI; slot += 64) out[slot] = first;
  }
}

// ---------------------------------------------------------------------------
// GEMM1 both branches in ONE kernel (8192 blocks). sem half XCD-swizzled:
// sbx = (bx&7)<<9 | bx>>3 keeps each batch's 4.2MB feat slice resident in
// ONE XCD's L2 during the gather (blocks of batch b land on XCD b).
// Bijective: 4096 = 8 x 512.
// ---------------------------------------------------------------------------
__global__ __launch_bounds__(256) void gemm1_both(const float* __restrict__ feat,
    const float* __restrict__ pos, const float* __restrict__ centers,
    const int* __restrict__ idx,
    const float* __restrict__ w_s, const float* __restrict__ b_s,
    float* __restrict__ h1s, float* __restrict__ st_s,
    const float* __restrict__ w_g, const float* __restrict__ b_g,
    float* __restrict__ h1g, float* __restrict__ st_g){
  __shared__ float smem[8448];           // union of both branch layouts
  const int tid = threadIdx.x;
  if (blockIdx.x < (MROWS/64)){
    // ------------------- sem branch -------------------
    float (*xst)[66] = (float(*)[66])smem;          // 64 (k) x 66 (r)
    float (*wsh)[64] = (float(*)[64])(smem + 4224); // 64x64
    const int sbx = ((blockIdx.x & 7) << 9) | (blockIdx.x >> 3);
    const int m0 = sbx * 64;
#pragma unroll
    for (int i = 0; i < 4; ++i){
      int q = tid + i*256;
      int r = q >> 4, c4 = q & 15;
      *(float4*)&wsh[r][c4*4] = *(const float4*)&w_s[r*64 + c4*4];
    }
#pragma unroll
    for (int i = 0; i < 4; ++i){
      int q = tid + i*256;
      int r = q >> 4, c4 = q & 15;
      int m = m0 + r;
      int nb = idx[m];
      int b = m >> 15;
      const float* fr = feat + ((size_t)b*NPTS + nb)*64;
      float4 v = *(const float4*)&fr[c4*4];
      xst[c4*4+0][r] = v.x;
      xst[c4*4+1][r] = v.y;
      xst[c4*4+2][r] = v.z;
      xst[c4*4+3][r] = v.w;
    }
    __syncthreads();
    const int g  = tid & 7;
    const int rt = tid >> 3;
    const int r0 = rt * 2;
    float acc[2][8];
#pragma unroll
    for (int c = 0; c < 8; ++c){ float bb = b_s[g*8+c]; acc[0][c] = bb; acc[1][c] = bb; }
    for (int k = 0; k < 64; ++k){
      float x0 = xst[k][r0], x1 = xst[k][r0+1];
      float4 wa = *(float4*)&wsh[k][g*8];
      float4 wb = *(float4*)&wsh[k][g*8+4];
      float wv[8] = {wa.x,wa.y,wa.z,wa.w,wb.x,wb.y,wb.z,wb.w};
#pragma unroll
      for (int c = 0; c < 8; ++c){ acc[0][c] += x0*wv[c]; acc[1][c] += x1*wv[c]; }
    }
#pragma unroll
    for (int r = 0; r < 2; ++r){
      float* dst = h1s + (size_t)(m0 + r0 + r)*64 + g*8;
      *(float4*)dst     = make_float4(acc[r][0],acc[r][1],acc[r][2],acc[r][3]);
      *(float4*)(dst+4) = make_float4(acc[r][4],acc[r][5],acc[r][6],acc[r][7]);
    }
    float ls[8], lq[8];
#pragma unroll
    for (int c = 0; c < 8; ++c){
      ls[c] = acc[0][c] + acc[1][c];
      lq[c] = acc[0][c]*acc[0][c] + acc[1][c]*acc[1][c];
    }
    __syncthreads();
    float* red  = smem;
    float* redq = smem + 4224;
#pragma unroll
    for (int c = 0; c < 8; ++c){
      red[(g*8+c)*32 + rt]  = ls[c];
      redq[(g*8+c)*32 + rt] = lq[c];
    }
    __syncthreads();
    if (tid < 128){
      int c = tid & 63;
      const float* src = (tid < 64) ? red : redq;
      float a2 = 0.f;
      for (int i = 0; i < 32; ++i) a2 += src[c*32+i];
      atomicAdd(&st_s[(tid < 64 ? 0 : 64) + c], a2);
    }
  } else {
    // ------------------- geo branch -------------------
    float (*xs)[8]   = (float(*)[8])smem;            // 64x8
    float (*wsh)[64] = (float(*)[64])(smem + 512);   // 6x64
    float* red  = smem + 896;                        // 2048
    float* redq = smem + 2944;                       // 2048
    const int m0 = (blockIdx.x - (MROWS/64)) * 64;
    for (int i = tid; i < 384; i += 256) wsh[i >> 6][i & 63] = w_g[i];
    if (tid < 64){
      int m = m0 + tid;
      int grp = m >> 5;
      int b = m >> 15;
      int nb = idx[m];
      const float* cp = centers + (size_t)grp*3;
      const float* pp = pos + ((size_t)b*NPTS + nb)*3;
      xs[tid][0]=cp[0]; xs[tid][1]=cp[1]; xs[tid][2]=cp[2];
      xs[tid][3]=pp[0]; xs[tid][4]=pp[1]; xs[tid][5]=pp[2];
    }
    __syncthreads();
    const int g  = tid & 7;
    const int rt = tid >> 3;
    const int r0 = rt * 2;
    float acc[2][8];
#pragma unroll
    for (int c = 0; c < 8; ++c){ float bb = b_g[g*8+c]; acc[0][c]=bb; acc[1][c]=bb; }
#pragma unroll
    for (int k = 0; k < 6; ++k){
      float x0 = xs[r0][k], x1 = xs[r0+1][k];
      float4 wa = *(float4*)&wsh[k][g*8];
      float4 wb = *(float4*)&wsh[k][g*8+4];
      float wv[8] = {wa.x,wa.y,wa.z,wa.w,wb.x,wb.y,wb.z,wb.w};
#pragma unroll
      for (int c = 0; c < 8; ++c){ acc[0][c] += x0*wv[c]; acc[1][c] += x1*wv[c]; }
    }
#pragma unroll
    for (int r = 0; r < 2; ++r){
      float* dst = h1g + (size_t)(m0 + r0 + r)*64 + g*8;
      *(float4*)dst     = make_float4(acc[r][0],acc[r][1],acc[r][2],acc[r][3]);
      *(float4*)(dst+4) = make_float4(acc[r][4],acc[r][5],acc[r][6],acc[r][7]);
    }
    float ls[8], lq[8];
#pragma unroll
    for (int c = 0; c < 8; ++c){
      ls[c] = acc[0][c] + acc[1][c];
      lq[c] = acc[0][c]*acc[0][c] + acc[1][c]*acc[1][c];
    }
#pragma unroll
    for (int c = 0; c < 8; ++c){
      red[(g*8+c)*32 + rt]  = ls[c];
      redq[(g*8+c)*32 + rt] = lq[c];
    }
    __syncthreads();
    if (tid < 128){
      int c = tid & 63;
      const float* src = (tid < 64) ? red : redq;
      float a2 = 0.f;
      for (int i = 0; i < 32; ++i) a2 += src[c*32+i];
      atomicAdd(&st_g[(tid < 64 ? 0 : 64) + c], a2);
    }
  }
}

// ---------------------------------------------------------------------------
// GEMM2 both branches (8192 blocks), fused max-over-k, BN1 fold computed
// IN-BLOCK from layer-1 stats. x-tile transposed (xst[k][r], 66-wide).
// Monotone-affine max commutation (a>0) as r16.
// ---------------------------------------------------------------------------
__global__ __launch_bounds__(256) void gemm2_both(
    const float* __restrict__ h1s, const float* __restrict__ st1,
    const float* __restrict__ g1,  const float* __restrict__ be1,
    const float* __restrict__ w_s2, const float* __restrict__ b_s2,
    float* __restrict__ hmax1, float* __restrict__ st2,
    const float* __restrict__ h1g, const float* __restrict__ st3,
    const float* __restrict__ g3,  const float* __restrict__ be3,
    const float* __restrict__ w_g2, const float* __restrict__ b_g2,
    float* __restrict__ hmax2, float* __restrict__ st4){
  __shared__ float smem[12416];          // xst 4224 | wsh 8192
  __shared__ float abuf[64], dbuf[64];
  const int tid = threadIdx.x;
  const bool sem = blockIdx.x < (MROWS/64);
  const int bx = sem ? blockIdx.x : blockIdx.x - (MROWS/64);
  const float* hin  = sem ? h1s  : h1g;
  const float* w    = sem ? w_s2 : w_g2;
  const float* bias = sem ? b_s2 : b_g2;
  float* hmax       = sem ? hmax1 : hmax2;
  float* stat       = sem ? st2  : st4;
  float (*xst)[66]  = (float(*)[66])smem;
  float (*wsh)[128] = (float(*)[128])(smem + 4224);
  const int m0 = bx * 64;
  // BN1 fold from stats (identical math to old bn_finalize)
  if (tid < 64){
    const float* st  = sem ? st1 : st3;
    const float* gam = sem ? g1  : g3;
    const float* bet = sem ? be1 : be3;
    const float invM = 1.0f / (float)MROWS;
    float mu  = st[tid] * invM;
    float ex2 = st[64 + tid] * invM;
    float var = ex2 - mu*mu;
    float aa = gam[tid] * rsqrtf(var + 1e-5f);
    abuf[tid] = aa;
    dbuf[tid] = bet[tid] - mu*aa;
  }
  __syncthreads();
#pragma unroll
  for (int i = 0; i < 8; ++i){
    int q = tid + i*256;                 // 2048 quads of w (64x128)
    int r = q >> 5, c4 = q & 31;
    *(float4*)&wsh[r][c4*4] = *(const float4*)&w[r*128 + c4*4];
  }
#pragma unroll
  for (int i = 0; i < 4; ++i){
    int q = tid + i*256;
    int r = q >> 4, c4 = q & 15;
    float4 v = *(const float4*)&hin[(size_t)(m0+r)*64 + c4*4];
    float a0 = abuf[c4*4+0], aA = abuf[c4*4+1], aB = abuf[c4*4+2], aC = abuf[c4*4+3];
    float d0 = dbuf[c4*4+0], dA = dbuf[c4*4+1], dB = dbuf[c4*4+2], dC = dbuf[c4*4+3];
    v.x = fmaxf(v.x*a0 + d0, 0.f);
    v.y = fmaxf(v.y*aA + dA, 0.f);
    v.z = fmaxf(v.z*aB + dB, 0.f);
    v.w = fmaxf(v.w*aC + dC, 0.f);
    xst[c4*4+0][r] = v.x;
    xst[c4*4+1][r] = v.y;
    xst[c4*4+2][r] = v.z;
    xst[c4*4+3][r] = v.w;
  }
  __syncthreads();
  const int g  = tid & 15;               // 16 groups x 8 ch = 128
  const int rt = tid >> 4;               // 16 row-threads x 4 rows = 64
  const int r0 = rt * 4;
  float acc[4][8];
#pragma unroll
  for (int c = 0; c < 8; ++c){
    float bb = bias[g*8+c];
    acc[0][c]=bb; acc[1][c]=bb; acc[2][c]=bb; acc[3][c]=bb;
  }
  for (int k = 0; k < 64; ++k){
    float x0 = xst[k][r0], x1 = xst[k][r0+1], x2 = xst[k][r0+2], x3 = xst[k][r0+3];
    float4 wa = *(float4*)&wsh[k][g*8];
    float4 wb = *(float4*)&wsh[k][g*8+4];
    float wv[8] = {wa.x,wa.y,wa.z,wa.w,wb.x,wb.y,wb.z,wb.w};
#pragma unroll
    for (int c = 0; c < 8; ++c){
      acc[0][c] += x0*wv[c]; acc[1][c] += x1*wv[c];
      acc[2][c] += x2*wv[c]; acc[3][c] += x3*wv[c];
    }
  }
  float ls[8], lq[8], tmax[8];
#pragma unroll
  for (int c = 0; c < 8; ++c){
    ls[c] = acc[0][c]+acc[1][c]+acc[2][c]+acc[3][c];
    lq[c] = acc[0][c]*acc[0][c]+acc[1][c]*acc[1][c]+acc[2][c]*acc[2][c]+acc[3][c]*acc[3][c];
    tmax[c] = fmaxf(fmaxf(acc[0][c],acc[1][c]), fmaxf(acc[2][c],acc[3][c]));
  }
  __syncthreads();
  float* red  = smem;                    // 2048 sums + 2048 sumsq (xst area)
  float* mred = smem + 4224;             // 16 x 128 maxes (wsh area)
#pragma unroll
  for (int c = 0; c < 8; ++c){
    red[(g*8+c)*16 + rt]        = ls[c];
    red[2048 + (g*8+c)*16 + rt] = lq[c];
    mred[rt*128 + g*8 + c]      = tmax[c];
  }
  __syncthreads();
  {
    int c = tid & 127;
    int isq = tid >> 7;
    float a2 = 0.f;
    for (int i = 0; i < 16; ++i) a2 += red[isq*2048 + c*16 + i];
    atomicAdd(&stat[isq*128 + c], a2);
  }
  {
    int og = tid >> 7;                   // 0..1 (k-group within block)
    int c  = tid & 127;
    float m = -3.4e38f;
#pragma unroll
    for (int i = 0; i < 8; ++i) m = fmaxf(m, mred[(og*8 + i)*128 + c]);
    hmax[(size_t)(bx*2 + og)*128 + c] = m;
  }
}

// ---------------------------------------------------------------------------
// BN apply on pooled maxes, BN2 fold computed per-thread from stats.
// Exact: a>0 monotone affine.
// ---------------------------------------------------------------------------
__global__ __launch_bounds__(256) void bnapply_both(const float* __restrict__ hmax1,
    const float* __restrict__ st2, const float* __restrict__ g2,
    const float* __restrict__ be2,
    const float* __restrict__ hmax2,
    const float* __restrict__ st4, const float* __restrict__ g4,
    const float* __restrict__ be4,
    float* __restrict__ out){
  const int half = NB*S*128;
  int i = blockIdx.x*256 + threadIdx.x;
  bool semh = i < half;
  int j = semh ? i : i - half;
  int c = j & 127;
  const float* st  = semh ? st2 : st4;
  const float* gam = semh ? g2  : g4;
  const float* bet = semh ? be2 : be4;
  const float invM = 1.0f / (float)MROWS;
  float mu  = st[c] * invM;
  float ex2 = st[128 + c] * invM;
  float var = ex2 - mu*mu;
  float aa = gam[c] * rsqrtf(var + 1e-5f);
  float dd = bet[c] - mu*aa;
  float hv = semh ? hmax1[j] : hmax2[j];
  out[i] = fmaxf(hv*aa + dd, 0.f);
}

extern "C" void kernel_launch(void* const* d_in, const int* in_sizes, int n_in,
                              void* d_out, int out_size, void* d_ws, size_t ws_size,
                              hipStream_t stream){
  const float* pos   = (const float*)d_in[0];
  const float* feat  = (const float*)d_in[1];
  const float* w_s1  = (const float*)d_in[2];
  const float* b_s1  = (const float*)d_in[3];
  const float* g_s1  = (const float*)d_in[4];
  const float* be_s1 = (const float*)d_in[5];
  const float* w_s2  = (const float*)d_in[6];
  const float* b_s2  = (const float*)d_in[7];
  const float* g_s2  = (const float*)d_in[8];
  const float* be_s2 = (const float*)d_in[9];
  const float* w_g1  = (const float*)d_in[10];
  const float* b_g1  = (const float*)d_in[11];
  const float* g_g1  = (const float*)d_in[12];
  const float* be_g1 = (const float*)d_in[13];
  const float* w_g2  = (const float*)d_in[14];
  const float* b_g2  = (const float*)d_in[15];
  const float* g_g2  = (const float*)d_in[16];
  const float* be_g2 = (const float*)d_in[17];
  float* outp = (float*)d_out;
  float* wsf  = (float*)d_ws;

  // workspace layout (floats):
  float* centers = wsf;                          // 24576
  int*   idxp    = (int*)(wsf + 24576);          // 262144
  float* stats   = wsf + 24576 + 262144;         // 768
  float* h1s     = wsf + 288256;                 // MROWS*64 = 16777216
  float* h1g     = h1s + (size_t)MROWS*64;       // 16777216
  float* sortbuf = h1g + (size_t)MROWS*64;       // 393216
  float* hmax1   = sortbuf + 393216;             // 1048576
  float* hmax2   = hmax1 + 1048576;              // 1048576

  float* st1 = stats;        // 64 sum + 64 sq
  float* st2 = stats + 128;  // 128 + 128
  float* st3 = stats + 384;  // 64 + 64
  float* st4 = stats + 512;  // 128 + 128

  fps_kernel<<<NB, 1024, 0, stream>>>(pos, centers, sortbuf);
  ballq_kernel<<<(NB*S)/4, 256, 0, stream>>>(pos, centers, idxp, stats);
  gemm1_both<<<2*(MROWS/64), 256, 0, stream>>>(feat, pos, centers, idxp,
      w_s1, b_s1, h1s, st1, w_g1, b_g1, h1g, st3);
  gemm2_both<<<2*(MROWS/64), 256, 0, stream>>>(
      h1s, st1, g_s1, be_s1, w_s2, b_s2, hmax1, st2,
      h1g, st3, g_g1, be_g1, w_g2, b_g2, hmax2, st4);
  bnapply_both<<<(2*NB*S*128)/256, 256, 0, stream>>>(
      hmax1, st2, g_s2, be_s2, hmax2, st4, g_g2, be_g2, outp);
}